// Round 11
// baseline (15511.024 us; speedup 1.0000x reference)
//
#include <hip/hip_runtime.h>
#include <math.h>

#define HID 512
#define B 64
#define SEQT 1024
#define FUT 16
#define TT (SEQT + FUT)
#define NWG 256
#define TPB 512          // fallback path block size
#define TPB1 1024        // main kernel block size (16 waves, 4/SIMD)
#define NWAVE1 16
#define JPW 2            // fallback: hidden units per WG
#define HB (HID * B)     // fallback h buffer floats

// ---- r11 split-grid constants: 2 independent groups of 128 WGs ----
#define GB 32            // batches per group
#define GWG 128          // WGs per group
#define GHB (HID * GB)   // one h buffer per group = 16384 floats
#define BLOB2 24576      // floats per lwg: 8192 (phase1 [k][16]) + 16384 (phase2 [k][32])

typedef __attribute__((ext_vector_type(2))) float f2;   // v_pk_fma_f32 pairs

// ws float layout (main path):
//   [0..511]            barrier slots (ints): group g slot lwg at int g*128+lwg
//   [512 .. +2*2*GHB)   h1 buffers: [group][dbuf][k>>2][b][k&3]
//   [.. +2*2*GHB)       h2 buffers: same layout
//   [.. +GWG*BLOB2)     weight blobs per lwg (SHARED by both groups)
//   [.. +SEQT*B)        xT (x transposed to [t][b]), all 64 batches
//   [.. +2*SEQT*GWG*GB) deferred-output partials per group [t][lwg][b]
#define WS_H1_F   512
#define WS_H2_F   (WS_H1_F + 2 * 2 * GHB)
#define WS_BLOB_F (WS_H2_F + 2 * 2 * GHB)
#define WS_XT_F   (WS_BLOB_F + GWG * BLOB2)
#define WS_TOT_F  (WS_XT_F + SEQT * B)
#define WS_PART_F WS_TOT_F
#define WS_TOT2_F (WS_PART_F + (size_t)2 * SEQT * GWG * GB)

// write-through publish (r6 win: no buffer_wbl2 in the hot path)
__device__ inline void pub_store(float* p, float v) {
  __hip_atomic_store(p, v, __ATOMIC_RELAXED, __HIP_MEMORY_SCOPE_AGENT);
}

// ---- group-local grid barrier: 128 slot stores + every WG polls 128 slots --
// Rules from r2-r10: no RMW arrivals; relaxed spin loads; ONE pre-spin
// acquire fence (inv) per WG per barrier.
__device__ inline void gbar6(int* bb, int gbase, int lwg, int bar) {
  __builtin_amdgcn_s_waitcnt(0);   // drain own write-through stores
  __syncthreads();
  const int tid = threadIdx.x;
  if (tid == 0) {
    __hip_atomic_store(bb + gbase + lwg, bar, __ATOMIC_RELAXED, __HIP_MEMORY_SCOPE_AGENT);
    __builtin_amdgcn_fence(__ATOMIC_ACQUIRE, "agent");  // pre-spin inv, once
  }
  if (tid < 64) {                  // wave 0 polls this group's 128 slots
    for (;;) {
      int a = __hip_atomic_load(bb + gbase + tid,      __ATOMIC_RELAXED, __HIP_MEMORY_SCOPE_AGENT);
      int b = __hip_atomic_load(bb + gbase + 64 + tid, __ATOMIC_RELAXED, __HIP_MEMORY_SCOPE_AGENT);
      if (__all(a >= bar && b >= bar)) break;
      __builtin_amdgcn_s_sleep(1);
    }
  }
  __syncthreads();
}

// ---------------- prep: zero state, rearrange weights, transpose x -----------
__global__ void __launch_bounds__(256) prep_ws(
    const float* __restrict__ x,
    const float* __restrict__ U1, const float* __restrict__ W2,
    const float* __restrict__ U2, float* __restrict__ ws)
{
  const int idx = blockIdx.x * blockDim.x + threadIdx.x;
  if (idx < WS_BLOB_F) ws[idx] = 0.0f;         // barrier + h buffers
  {
    const int i2 = idx - WS_BLOB_F;
    if (i2 >= 0 && i2 < GWG * BLOB2) {
      const int lwg = i2 / BLOB2;
      const int off = i2 - lwg * BLOB2;
      const int j0  = lwg * 4;
      float v;
      if (off < 8192) {                        // phase1: [k*16 + r] = U1[row(r)][k]
        const int k = off >> 4, r = off & 15;
        const int row = (r >> 2) * HID + j0 + (r & 3);
        v = U1[(size_t)row * HID + k];
      } else {                                 // phase2: [k*32 + rr]
        const int o2 = off - 8192;
        const int k = o2 >> 5, rr = o2 & 31;
        const int r = rr & 15;
        const int row = (r >> 2) * HID + j0 + (r & 3);
        v = (rr < 16) ? W2[(size_t)row * HID + k] : U2[(size_t)row * HID + k];
      }
      ws[WS_BLOB_F + i2] = v;
    }
  }
  {
    const int i3 = idx - WS_XT_F;
    if (i3 >= 0 && i3 < SEQT * B) {
      const int t = i3 >> 6, b = i3 & 63;
      ws[WS_XT_F + i3] = x[(size_t)b * SEQT + t];
    }
  }
}

// ------- persistent 2-layer LSTM: two decoupled 128-WG groups (batch split) --
// Group g owns batches [g*32, g*32+32). WG lwg owns 4 hidden units.
// Wave wvu owns k-chunk [wvu*32,+32); lane=(khalf,b): k-sub of 16 for batch b.
// phase1 uses register-carried h1(t-1); phase2 reloads h1(t),h2(t-1) post-bar.
__global__ void __launch_bounds__(TPB1, 1) rnn_main(
    const float* __restrict__ W1, const float* __restrict__ bW1,
    const float* __restrict__ bU1,
    const float* __restrict__ bW2, const float* __restrict__ bU2,
    const float* __restrict__ lw, const float* __restrict__ lb,
    float* __restrict__ out,
    int* __restrict__ bb,
    float* __restrict__ h1b, float* __restrict__ h2b,
    const float* __restrict__ wbl, const float* __restrict__ xT,
    float* __restrict__ part, int defer)
{
  __shared__ float wlds[BLOB2];          // 96 KB persistent weight blob
  __shared__ float red[NWAVE1][16][GB];  // per-wave partial dots, 32 KB
  __shared__ float outred[NWAVE1][GB];   // output-head reduction, 2 KB
  __shared__ float c1s[4][GB], c2s[4][GB];
  __shared__ float pout[4][GB];          // per-step output partial staging
  __shared__ float w1c[16], bs1[16], bs2[16], lwc[4];

  const int wg    = blockIdx.x;
  const int g     = wg >> 7;
  const int lwg   = wg & 127;
  const int gbase = g << 7;
  const int boff  = g * GB;
  const int j0    = lwg * 4;
  const int tid   = threadIdx.x;
  const int lane  = tid & 63;
  const int wvu   = __builtin_amdgcn_readfirstlane(tid >> 6);
  const int khalf = lane >> 5;       // 0/1: which 16-k half of the wave's 32-k
  const int b     = lane & 31;       // batch within group

  // ---- one-time: copy this lwg's weight blob into LDS (shared by groups) ----
  {
    const float4* gsrc = (const float4*)(wbl + (size_t)lwg * BLOB2);
    float4* ldst = (float4*)wlds;
    #pragma unroll
    for (int i = 0; i < BLOB2 / 4 / TPB1; ++i)
      ldst[i * TPB1 + tid] = gsrc[i * TPB1 + tid];
  }
  if (tid < 4 * GB) { c1s[tid >> 5][tid & 31] = 0.f; c2s[tid >> 5][tid & 31] = 0.f; }
  if (tid < 16) {
    const int gi = tid >> 2, jl = tid & 3;
    const int row = gi * HID + j0 + jl;
    w1c[tid] = W1[row];
    bs1[tid] = bW1[row] + bU1[row];
    bs2[tid] = bW2[row] + bU2[row];
  }
  if (tid < 4) lwc[tid] = lw[j0 + tid];
  __syncthreads();

  const float* wl1 = wlds + wvu * 512 + khalf * 256;           // [k][16]
  const float* wl2 = wlds + 8192 + wvu * 1024 + khalf * 512;   // [k][32]
  const float lbv = lb[0];

  float* h1g = h1b + (size_t)g * 2 * GHB;
  float* h2g = h2b + (size_t)g * 2 * GHB;
  float* partg = part + (size_t)g * SEQT * GWG * GB;

  float4 H1[4], Q[4];                  // h1 carry + h2old staging (16 k each)
  #pragma unroll
  for (int i = 0; i < 4; ++i) H1[i] = make_float4(0.f, 0.f, 0.f, 0.f);

  int bar = 0;
  for (int t = 0; t < TT; ++t) {
    float*       h1new = h1g + (t & 1) * GHB;
    const float* h2old = h2g + ((t + 1) & 1) * GHB;
    float*       h2new = h2g + (t & 1) * GHB;

    // prefetch x for cell-1 (teacher region)
    float xvpref = 0.f;
    if (tid < 4 * GB && t < SEQT) xvpref = xT[(size_t)t * B + boff + (tid & 31)];

    // -------- phase 1: gates1 = U1 h1(t-1), h1(t-1) in H1 registers ---------
    {
      float h1a[16];
      #pragma unroll
      for (int i = 0; i < 4; ++i) {
        h1a[4*i+0] = H1[i].x; h1a[4*i+1] = H1[i].y;
        h1a[4*i+2] = H1[i].z; h1a[4*i+3] = H1[i].w;
      }
      f2 a[8];
      #pragma unroll
      for (int r = 0; r < 8; ++r) a[r] = (f2){0.f, 0.f};
      #pragma unroll
      for (int kk = 0; kk < 16; ++kk) {
        const float4* wr = (const float4*)(wl1 + kk * 16);
        const f2 hs = {h1a[kk], h1a[kk]};
        const float4 w0 = wr[0], w1 = wr[1], w2 = wr[2], w3 = wr[3];
        a[0] = __builtin_elementwise_fma((f2){w0.x, w0.y}, hs, a[0]);
        a[1] = __builtin_elementwise_fma((f2){w0.z, w0.w}, hs, a[1]);
        a[2] = __builtin_elementwise_fma((f2){w1.x, w1.y}, hs, a[2]);
        a[3] = __builtin_elementwise_fma((f2){w1.z, w1.w}, hs, a[3]);
        a[4] = __builtin_elementwise_fma((f2){w2.x, w2.y}, hs, a[4]);
        a[5] = __builtin_elementwise_fma((f2){w2.z, w2.w}, hs, a[5]);
        a[6] = __builtin_elementwise_fma((f2){w3.x, w3.y}, hs, a[6]);
        a[7] = __builtin_elementwise_fma((f2){w3.z, w3.w}, hs, a[7]);
      }
      // combine the two 16-k halves (lane ^ 32); both halves get the sum
      #pragma unroll
      for (int r = 0; r < 8; ++r) {
        a[r].x += __shfl_xor(a[r].x, 32);
        a[r].y += __shfl_xor(a[r].y, 32);
      }
      // khalf0 writes rows 0..7 (a[0..3]), khalf1 rows 8..15 (a[4..7])
      #pragma unroll
      for (int i = 0; i < 4; ++i) {
        red[wvu][khalf * 8 + 2*i][b]     = a[khalf * 4 + i].x;
        red[wvu][khalf * 8 + 2*i + 1][b] = a[khalf * 4 + i].y;
      }
    }
    __syncthreads();

    // cell-1 elementwise (4 j's x 32 b = 128 threads)
    if (tid < 4 * GB) {
      const int jl = tid >> 5, bb_ = tid & 31;
      const float xv = (t < SEQT) ? xvpref
                                  : out[(size_t)(boff + bb_) * TT + (t - 1)];
      float gate[4];
      #pragma unroll
      for (int gi = 0; gi < 4; ++gi) {
        const int r = gi * 4 + jl;
        float s = bs1[r] + xv * w1c[r];
        #pragma unroll
        for (int w = 0; w < NWAVE1; ++w) s += red[w][r][bb_];
        gate[gi] = s;
      }
      const float c = gate[1] * c1s[jl][bb_] + gate[0] * gate[2];
      c1s[jl][bb_] = c;
      pub_store(&h1new[lwg * (GB * 4) + bb_ * 4 + jl], gate[3] * tanhf(c));
    }

    ++bar;
    gbar6(bb, gbase, lwg, bar);

    // non-defer mode only: duty WG computes output head inline
    if (!defer && lwg == (t & 127) && t >= 1 && t <= SEQT - 1) {
      const float4* hb = (const float4*)h2old + (size_t)(wvu * 8 + khalf * 4) * GB + b;
      const float4* lw4 = (const float4*)lw + wvu * 8 + khalf * 4;
      float p = 0.f;
      #pragma unroll
      for (int i = 0; i < 4; ++i) {
        const float4 hv = hb[i * GB];
        const float4 wv = lw4[i];
        p = fmaf(wv.x, hv.x, p); p = fmaf(wv.y, hv.y, p);
        p = fmaf(wv.z, hv.z, p); p = fmaf(wv.w, hv.w, p);
      }
      p += __shfl_xor(p, 32);
      if (khalf == 0) outred[wvu][b] = p;
      __syncthreads();
      if (tid < GB) {
        float o = lbv;
        #pragma unroll
        for (int s = 0; s < NWAVE1; ++s) o += outred[s][tid];
        pub_store(&out[(size_t)(boff + tid) * TT + (t - 1)], o);
      }
      __syncthreads();
    }

    // -------- phase 2: gates2 = W2 h1(t) + U2 h2(t-1) ------------------------
    {
      const float4* p4 = (const float4*)h1new + (size_t)(wvu * 8 + khalf * 4) * GB + b;
      const float4* q4 = (const float4*)h2old + (size_t)(wvu * 8 + khalf * 4) * GB + b;
      #pragma unroll
      for (int i = 0; i < 4; ++i) H1[i] = p4[i * GB];
      #pragma unroll
      for (int i = 0; i < 4; ++i) Q[i] = q4[i * GB];
      float h1a[16], h2a[16];
      #pragma unroll
      for (int i = 0; i < 4; ++i) {
        h1a[4*i+0] = H1[i].x; h1a[4*i+1] = H1[i].y;
        h1a[4*i+2] = H1[i].z; h1a[4*i+3] = H1[i].w;
        h2a[4*i+0] = Q[i].x;  h2a[4*i+1] = Q[i].y;
        h2a[4*i+2] = Q[i].z;  h2a[4*i+3] = Q[i].w;
      }
      f2 a[8];
      #pragma unroll
      for (int r = 0; r < 8; ++r) a[r] = (f2){0.f, 0.f};
      #pragma unroll
      for (int kk = 0; kk < 16; ++kk) {
        const float4* wr = (const float4*)(wl2 + kk * 32);
        const f2 hs1 = {h1a[kk], h1a[kk]};
        const f2 hs2 = {h2a[kk], h2a[kk]};
        #pragma unroll
        for (int m = 0; m < 4; ++m) {         // W2 rows 0..15
          const float4 w = wr[m];
          a[2*m]   = __builtin_elementwise_fma((f2){w.x, w.y}, hs1, a[2*m]);
          a[2*m+1] = __builtin_elementwise_fma((f2){w.z, w.w}, hs1, a[2*m+1]);
        }
        #pragma unroll
        for (int m = 0; m < 4; ++m) {         // U2 rows 16..31
          const float4 w = wr[4 + m];
          a[2*m]   = __builtin_elementwise_fma((f2){w.x, w.y}, hs2, a[2*m]);
          a[2*m+1] = __builtin_elementwise_fma((f2){w.z, w.w}, hs2, a[2*m+1]);
        }
      }
      #pragma unroll
      for (int r = 0; r < 8; ++r) {
        a[r].x += __shfl_xor(a[r].x, 32);
        a[r].y += __shfl_xor(a[r].y, 32);
      }
      #pragma unroll
      for (int i = 0; i < 4; ++i) {
        red[wvu][khalf * 8 + 2*i][b]     = a[khalf * 4 + i].x;
        red[wvu][khalf * 8 + 2*i + 1][b] = a[khalf * 4 + i].y;
      }
    }
    __syncthreads();

    // cell-2 elementwise
    if (tid < 4 * GB) {
      const int jl = tid >> 5, bb_ = tid & 31;
      float gate[4];
      #pragma unroll
      for (int gi = 0; gi < 4; ++gi) {
        const int r = gi * 4 + jl;
        float s = bs2[r];
        #pragma unroll
        for (int w = 0; w < NWAVE1; ++w) s += red[w][r][bb_];
        gate[gi] = s;
      }
      const float c = gate[1] * c2s[jl][bb_] + gate[0] * gate[2];
      c2s[jl][bb_] = c;
      const float h2v = gate[3] * tanhf(c);
      pub_store(&h2new[lwg * (GB * 4) + bb_ * 4 + jl], h2v);
      if (defer && t < SEQT) pout[jl][bb_] = lwc[jl] * h2v;
    }
    __syncthreads();  // protect red[] + publish pout

    // deferred-output partial store: 32 floats/WG/step
    if (defer && t < SEQT && tid < GB) {
      pub_store(&partg[((size_t)t * GWG + lwg) * GB + tid],
                pout[0][tid] + pout[1][tid] + pout[2][tid] + pout[3][tid]);
    }

    // Autoregressive region: out(t) must be visible before phase1(t+1)
    if (t >= SEQT - 1) {
      ++bar;
      gbar6(bb, gbase, lwg, bar);
      if (lwg == 0) {
        const float4* hb = (const float4*)h2new + (size_t)(wvu * 8 + khalf * 4) * GB + b;
        const float4* lw4 = (const float4*)lw + wvu * 8 + khalf * 4;
        float p = 0.f;
        #pragma unroll
        for (int i = 0; i < 4; ++i) {
          const float4 hv = hb[i * GB];
          const float4 wv = lw4[i];
          p = fmaf(wv.x, hv.x, p); p = fmaf(wv.y, hv.y, p);
          p = fmaf(wv.z, hv.z, p); p = fmaf(wv.w, hv.w, p);
        }
        p += __shfl_xor(p, 32);
        if (khalf == 0) outred[wvu][b] = p;
        __syncthreads();
        if (tid < GB) {
          float o = lbv;
          #pragma unroll
          for (int s = 0; s < NWAVE1; ++s) o += outred[s][tid];
          pub_store(&out[(size_t)(boff + tid) * TT + t], o);
        }
        __syncthreads();
      }
      ++bar;
      gbar6(bb, gbase, lwg, bar);
    }
  }

  // ---- defer mode tail: parallel reduction of output partials (t=0..1022) --
  if (defer) {
    ++bar;
    gbar6(bb, gbase, lwg, bar);   // all partial stores visible + L2 inv'd
    for (int tt = lwg; tt < SEQT - 1; tt += GWG) {
      const float* pp = partg + ((size_t)tt * GWG + wvu * 8 + khalf * 4) * GB + b;
      float s = 0.f;
      #pragma unroll
      for (int i = 0; i < 4; ++i) s += pp[i * GB];
      s += __shfl_xor(s, 32);
      if (khalf == 0) outred[wvu][b] = s;
      __syncthreads();
      if (tid < GB) {
        float o = lbv;
        #pragma unroll
        for (int v = 0; v < NWAVE1; ++v) o += outred[v][tid];
        out[(size_t)(boff + tid) * TT + tt] = o;
      }
      __syncthreads();
    }
  }
}

// =================== fallback path (round-0 kernel, known correct) ===========
__device__ inline void gbar(int* cnt, int target) {
  __syncthreads();
  if (threadIdx.x == 0) {
    __threadfence();
    __hip_atomic_fetch_add(cnt, 1, __ATOMIC_RELEASE, __HIP_MEMORY_SCOPE_AGENT);
    while (__hip_atomic_load(cnt, __ATOMIC_ACQUIRE, __HIP_MEMORY_SCOPE_AGENT) < target) {
      __builtin_amdgcn_s_sleep(2);
    }
  }
  __syncthreads();
}

__global__ void __launch_bounds__(TPB) zero_ws(float* ws, int n) {
  int i = blockIdx.x * blockDim.x + threadIdx.x;
  if (i < n) ws[i] = 0.0f;
}

__global__ void __launch_bounds__(TPB) rnn_fallback(
    const float* __restrict__ x,
    const float* __restrict__ W1, const float* __restrict__ bW1,
    const float* __restrict__ U1, const float* __restrict__ bU1,
    const float* __restrict__ W2, const float* __restrict__ bW2,
    const float* __restrict__ U2, const float* __restrict__ bU2,
    const float* __restrict__ lw, const float* __restrict__ lb,
    float* out, float* ws)
{
  __shared__ float red[8][8][B];
  __shared__ float outred[8][B];
  __shared__ float c1s[JPW][B], c2s[JPW][B];
  __shared__ float w1c[8], bs1[8], bs2[8];

  int* cnt   = (int*)ws;
  float* h1b = ws + 16;
  float* h2b = h1b + 2 * HB;

  const int wg   = blockIdx.x;
  const int j0   = wg * JPW;
  const int tid  = threadIdx.x;
  const int lane = tid & 63;
  const int wvu  = __builtin_amdgcn_readfirstlane(tid >> 6);
  const int kb   = wvu << 6;

  if (tid < JPW * B) { c1s[tid >> 6][lane] = 0.f; c2s[tid >> 6][lane] = 0.f; }
  if (tid < 8) {
    const int g = tid >> 1, jl = tid & 1;
    const int row = g * HID + j0 + jl;
    w1c[tid] = W1[row];
    bs1[tid] = bW1[row] + bU1[row];
    bs2[tid] = bW2[row] + bU2[row];
  }
  __syncthreads();

  const float* u1p[8]; const float* w2p[8]; const float* u2p[8];
  #pragma unroll
  for (int r = 0; r < 8; ++r) {
    const int row = (r >> 1) * HID + j0 + (r & 1);
    u1p[r] = U1 + (size_t)row * HID + kb;
    w2p[r] = W2 + (size_t)row * HID + kb;
    u2p[r] = U2 + (size_t)row * HID + kb;
  }
  const float lbv = lb[0];

  int bar = 0;
  for (int t = 0; t < TT; ++t) {
    const float* h1old = h1b + ((t + 1) & 1) * HB;
    float*       h1new = h1b + (t & 1) * HB;
    const float* h2old = h2b + ((t + 1) & 1) * HB;
    float*       h2new = h2b + (t & 1) * HB;

    {
      const float* hp = h1old + (size_t)kb * B;
      float a0=0.f,a1=0.f,a2=0.f,a3=0.f,a4=0.f,a5=0.f,a6=0.f,a7=0.f;
      #pragma unroll 8
      for (int k = 0; k < 64; ++k) {
        const float hv = hp[k * B + lane];
        a0 = fmaf(u1p[0][k], hv, a0); a1 = fmaf(u1p[1][k], hv, a1);
        a2 = fmaf(u1p[2][k], hv, a2); a3 = fmaf(u1p[3][k], hv, a3);
        a4 = fmaf(u1p[4][k], hv, a4); a5 = fmaf(u1p[5][k], hv, a5);
        a6 = fmaf(u1p[6][k], hv, a6); a7 = fmaf(u1p[7][k], hv, a7);
      }
      red[wvu][0][lane]=a0; red[wvu][1][lane]=a1; red[wvu][2][lane]=a2; red[wvu][3][lane]=a3;
      red[wvu][4][lane]=a4; red[wvu][5][lane]=a5; red[wvu][6][lane]=a6; red[wvu][7][lane]=a7;
    }
    __syncthreads();

    if (tid < JPW * B) {
      const int jl = tid >> 6, b = tid & 63;
      const float xv = (t < SEQT) ? x[(size_t)b * SEQT + t]
                                  : out[(size_t)b * TT + (t - 1)];
      float gate[4];
      #pragma unroll
      for (int g = 0; g < 4; ++g) {
        const int r = g * 2 + jl;
        float s = bs1[r] + xv * w1c[r];
        #pragma unroll
        for (int w = 0; w < 8; ++w) s += red[w][r][b];
        gate[g] = s;
      }
      const float c = gate[1] * c1s[jl][b] + gate[0] * gate[2];
      c1s[jl][b] = c;
      h1new[(size_t)(j0 + jl) * B + b] = gate[3] * tanhf(c);
    }

    ++bar;
    gbar(cnt, NWG * bar);

    if (wg == 0 && t >= 1 && t <= SEQT - 1) {
      const float* hb2 = h2old + (size_t)(wvu * 64) * B;
      const float* lwp = lw + wvu * 64;
      float p = 0.f;
      #pragma unroll 8
      for (int j = 0; j < 64; ++j) p = fmaf(lwp[j], hb2[j * B + lane], p);
      outred[wvu][lane] = p;
      __syncthreads();
      if (tid < B) {
        float o = lbv;
        #pragma unroll
        for (int s = 0; s < 8; ++s) o += outred[s][tid];
        out[(size_t)tid * TT + (t - 1)] = o;
      }
      __syncthreads();
    }

    {
      const float* h1p = h1new + (size_t)kb * B;
      const float* h2p = h2old + (size_t)kb * B;
      float s0=0.f,s1=0.f,s2=0.f,s3=0.f,s4=0.f,s5=0.f,s6=0.f,s7=0.f;
      float q0=0.f,q1=0.f,q2=0.f,q3=0.f,q4=0.f,q5=0.f,q6=0.f,q7=0.f;
      #pragma unroll 4
      for (int k = 0; k < 64; ++k) {
        const float h1v = h1p[k * B + lane];
        const float h2v = h2p[k * B + lane];
        s0 = fmaf(w2p[0][k], h1v, s0); q0 = fmaf(u2p[0][k], h2v, q0);
        s1 = fmaf(w2p[1][k], h1v, s1); q1 = fmaf(u2p[1][k], h2v, q1);
        s2 = fmaf(w2p[2][k], h1v, s2); q2 = fmaf(u2p[2][k], h2v, q2);
        s3 = fmaf(w2p[3][k], h1v, s3); q3 = fmaf(u2p[3][k], h2v, q3);
        s4 = fmaf(w2p[4][k], h1v, s4); q4 = fmaf(u2p[4][k], h2v, q4);
        s5 = fmaf(w2p[5][k], h1v, s5); q5 = fmaf(u2p[5][k], h2v, q5);
        s6 = fmaf(w2p[6][k], h1v, s6); q6 = fmaf(u2p[6][k], h2v, q6);
        s7 = fmaf(w2p[7][k], h1v, s7); q7 = fmaf(u2p[7][k], h2v, q7);
      }
      red[wvu][0][lane]=s0+q0; red[wvu][1][lane]=s1+q1;
      red[wvu][2][lane]=s2+q2; red[wvu][3][lane]=s3+q3;
      red[wvu][4][lane]=s4+q4; red[wvu][5][lane]=s5+q5;
      red[wvu][6][lane]=s6+q6; red[wvu][7][lane]=s7+q7;
    }
    __syncthreads();

    if (tid < JPW * B) {
      const int jl = tid >> 6, b = tid & 63;
      float gate[4];
      #pragma unroll
      for (int g = 0; g < 4; ++g) {
        const int r = g * 2 + jl;
        float s = bs2[r];
        #pragma unroll
        for (int w = 0; w < 8; ++w) s += red[w][r][b];
        gate[g] = s;
      }
      const float c = gate[1] * c2s[jl][b] + gate[0] * gate[2];
      c2s[jl][b] = c;
      h2new[(size_t)(j0 + jl) * B + b] = gate[3] * tanhf(c);
    }
    __syncthreads();

    if (t >= SEQT - 1) {
      ++bar;
      gbar(cnt, NWG * bar);
      if (wg == 0) {
        const float* hb2 = h2new + (size_t)(wvu * 64) * B;
        const float* lwp = lw + wvu * 64;
        float p = 0.f;
        #pragma unroll 8
        for (int j = 0; j < 64; ++j) p = fmaf(lwp[j], hb2[j * B + lane], p);
        outred[wvu][lane] = p;
        __syncthreads();
        if (tid < B) {
          float o = lbv;
          #pragma unroll
          for (int s = 0; s < 8; ++s) o += outred[s][tid];
          out[(size_t)tid * TT + t] = o;
        }
        __syncthreads();
      }
      ++bar;
      gbar(cnt, NWG * bar);
    }
  }
}

extern "C" void kernel_launch(void* const* d_in, const int* in_sizes, int n_in,
                              void* d_out, int out_size, void* d_ws, size_t ws_size,
                              hipStream_t stream) {
  (void)in_sizes; (void)n_in; (void)out_size;
  const float* x   = (const float*)d_in[0];
  const float* W1  = (const float*)d_in[1];
  const float* bW1 = (const float*)d_in[2];
  const float* U1  = (const float*)d_in[3];
  const float* bU1 = (const float*)d_in[4];
  const float* W2  = (const float*)d_in[5];
  const float* bW2 = (const float*)d_in[6];
  const float* U2  = (const float*)d_in[7];
  const float* bU2 = (const float*)d_in[8];
  const float* lw  = (const float*)d_in[9];
  const float* lb  = (const float*)d_in[10];

  float* out = (float*)d_out;
  float* ws  = (float*)d_ws;

  if (ws_size >= (size_t)WS_TOT_F * sizeof(float)) {
    const int defer = (ws_size >= WS_TOT2_F * sizeof(float)) ? 1 : 0;
    prep_ws<<<(WS_TOT_F + 255) / 256, 256, 0, stream>>>(x, U1, W2, U2, ws);
    rnn_main<<<NWG, TPB1, 0, stream>>>(W1, bW1, bU1, bW2, bU2, lw, lb, out,
                                       (int*)ws, ws + WS_H1_F, ws + WS_H2_F,
                                       ws + WS_BLOB_F, ws + WS_XT_F,
                                       ws + WS_PART_F, defer);
  } else {
    const int nzero = 16 + 4 * HID * B;
    zero_ws<<<(nzero + TPB - 1) / TPB, TPB, 0, stream>>>(ws, nzero);
    rnn_fallback<<<NWG, TPB, 0, stream>>>(x, W1, bW1, U1, bU1,
                                          W2, bW2, U2, bU2, lw, lb, out, ws);
  }
}

// Round 12
// 13189.236 us; speedup vs baseline: 1.1760x; 1.1760x over previous
//
#include <hip/hip_runtime.h>
#include <math.h>

#define HID 512
#define B 64
#define SEQT 1024
#define FUT 16
#define TT (SEQT + FUT)
#define NWG 256
#define TPB 512          // fallback path block size
#define TPB1 1024        // main kernel block size (16 waves, 4/SIMD)
#define NWAVE1 16
#define JPW 2            // hidden units owned per WG = HID/NWG
#define HB (HID * B)     // one h buffer, floats
#define BLOBF 12288      // floats per WG: 4096 (U1 [k][8]) + 8192 ([k][W2 8|U2 8])

typedef __attribute__((ext_vector_type(2))) float f2;   // v_pk_fma_f32 pairs

// ws float layout (main path):
//   [0..511]               barrier block (ints): slot[wg] at int wg (wg<256)
//   [512 .. +2HB)          h1 double buffer  (float4 tiles: h4[k>>2][b][k&3])
//   [.. +2HB)              h2 double buffer  (same layout)
//   [.. +NWG*BLOBF)        rearranged weight blobs (per WG)
//   [.. +SEQT*B)           xT (x transposed to [t][b])
//   [.. +SEQT*NWG*B)       deferred-output partials part[t][wg][b] (defer mode)
#define WS_H1_F   512
#define WS_H2_F   (WS_H1_F + 2 * HB)
#define WS_BLOB_F (WS_H2_F + 2 * HB)
#define WS_XT_F   (WS_BLOB_F + NWG * BLOBF)
#define WS_TOT_F  (WS_XT_F + SEQT * B)
#define WS_PART_F WS_TOT_F
#define WS_TOT2_F (WS_PART_F + (size_t)SEQT * NWG * B)

// write-through publish (r6 win: no buffer_wbl2 in the hot path)
__device__ inline void pub_store(float* p, float v) {
  __hip_atomic_store(p, v, __ATOMIC_RELAXED, __HIP_MEMORY_SCOPE_AGENT);
}

// ---- grid barrier v5 (r8): slot stores + every WG polls all 256 slots ------
__device__ inline void gbar5(int* bb, int wg, int bar) {
  __builtin_amdgcn_s_waitcnt(0);   // all threads drain own write-through stores
  __syncthreads();
  const int tid = threadIdx.x;
  if (tid == 0) {
    __hip_atomic_store(bb + wg, bar, __ATOMIC_RELAXED, __HIP_MEMORY_SCOPE_AGENT);
    __builtin_amdgcn_fence(__ATOMIC_ACQUIRE, "agent");  // pre-spin inv, once
  }
  if (tid < 64) {
    for (;;) {
      int a = __hip_atomic_load(bb + tid,       __ATOMIC_RELAXED, __HIP_MEMORY_SCOPE_AGENT);
      int b = __hip_atomic_load(bb + 64  + tid, __ATOMIC_RELAXED, __HIP_MEMORY_SCOPE_AGENT);
      int c = __hip_atomic_load(bb + 128 + tid, __ATOMIC_RELAXED, __HIP_MEMORY_SCOPE_AGENT);
      int d = __hip_atomic_load(bb + 192 + tid, __ATOMIC_RELAXED, __HIP_MEMORY_SCOPE_AGENT);
      if (__all(a >= bar && b >= bar && c >= bar && d >= bar)) break;
      __builtin_amdgcn_s_sleep(1);
    }
  }
  __syncthreads();
}

// ---------------- prep: zero state, rearrange weights, transpose x -----------
__global__ void __launch_bounds__(256) prep_ws(
    const float* __restrict__ x,
    const float* __restrict__ U1, const float* __restrict__ W2,
    const float* __restrict__ U2, float* __restrict__ ws)
{
  const int idx = blockIdx.x * blockDim.x + threadIdx.x;
  if (idx < WS_BLOB_F) ws[idx] = 0.0f;         // barrier + h buffers
  {
    const int i2 = idx - WS_BLOB_F;
    if (i2 >= 0 && i2 < NWG * BLOBF) {
      const int wg  = i2 / BLOBF;
      const int off = i2 - wg * BLOBF;
      const int j0  = wg * JPW;
      float v;
      if (off < 4096) {                        // U1 part: [k*8 + r] = U1[row(r)][k]
        const int k = off >> 3, r = off & 7;
        const int row = (r >> 1) * HID + j0 + (r & 1);
        v = U1[(size_t)row * HID + k];
      } else {                                 // phase2 part: [k*16 + rr]
        const int o2 = off - 4096;
        const int k = o2 >> 4, rr = o2 & 15;
        const int r = rr & 7;
        const int row = (r >> 1) * HID + j0 + (r & 1);
        v = (rr < 8) ? W2[(size_t)row * HID + k] : U2[(size_t)row * HID + k];
      }
      ws[WS_BLOB_F + i2] = v;
    }
  }
  {
    const int i3 = idx - WS_XT_F;
    if (i3 >= 0 && i3 < SEQT * B) {
      const int t = i3 >> 6, b = i3 & 63;
      ws[WS_XT_F + i3] = x[(size_t)b * SEQT + t];
    }
  }
}

// -------- persistent 2-layer LSTM, r12: single merged reduction per step -----
// Per step (teacher): barrier -> load h1(t),h2(t-1) -> compute ALL dots
// (U1*h1 for next cell1; W2*h1+U2*h2 for cell2) -> ONE sync -> cell2 (waves
// 0-1) || cell1(t+1) (waves 2-3) -> stores -> arrive. One serial reduce+cell
// segment per step instead of r10's two.
__global__ void __launch_bounds__(TPB1, 1) rnn_main(
    const float* __restrict__ W1, const float* __restrict__ bW1,
    const float* __restrict__ bU1,
    const float* __restrict__ bW2, const float* __restrict__ bU2,
    const float* __restrict__ lw, const float* __restrict__ lb,
    float* __restrict__ out,
    int* __restrict__ bb,
    float* __restrict__ h1b, float* __restrict__ h2b,
    const float* __restrict__ wbl, const float* __restrict__ xT,
    float* __restrict__ part, int defer)
{
  __shared__ float wlds[BLOBF];          // 48 KB persistent weight blob
  __shared__ float red[NWAVE1][16][B];   // rows 0-7: cell2; 8-15: next cell1 (64 KB)
  __shared__ float outred[NWAVE1][B];    // output-head reduction, 4 KB
  __shared__ float c1s[JPW][B], c2s[JPW][B];
  __shared__ float pout[JPW][B];         // per-step output partial staging
  __shared__ float w1c[8], bs1[8], bs2[8], lwc[JPW];

  const int wg   = blockIdx.x;
  const int j0   = wg * JPW;
  const int tid  = threadIdx.x;
  const int lane = tid & 63;
  const int wvu  = __builtin_amdgcn_readfirstlane(tid >> 6);

  // ---- one-time: copy this WG's weight blob into LDS ----
  {
    const float4* gsrc = (const float4*)(wbl + (size_t)wg * BLOBF);
    float4* ldst = (float4*)wlds;
    #pragma unroll
    for (int i = 0; i < BLOBF / 4 / TPB1; ++i)
      ldst[i * TPB1 + tid] = gsrc[i * TPB1 + tid];
  }
  if (tid < JPW * B) { c1s[tid >> 6][lane] = 0.f; c2s[tid >> 6][lane] = 0.f; }
  if (tid < 8) {
    const int g = tid >> 1, jl = tid & 1;
    const int row = g * HID + j0 + jl;
    w1c[tid] = W1[row];
    bs1[tid] = bW1[row] + bU1[row];
    bs2[tid] = bW2[row] + bU2[row];
  }
  if (tid < JPW) lwc[tid] = lw[j0 + tid];
  __syncthreads();

  const float* wl1 = wlds + wvu * 256;          // U1 [k][8], this wave's 32 k
  const float* wl2 = wlds + 4096 + wvu * 512;   // [k][W2 8|U2 8]
  const float lbv = lb[0];

  // ---- prologue: cell1(0) from h1(-1)=0 (gates = bs1 + x0*w1c) ----
  if (tid < JPW * B) {
    const int jl = tid >> 6, b = tid & 63;
    const float xv = xT[b];
    float gate[4];
    #pragma unroll
    for (int g = 0; g < 4; ++g) gate[g] = bs1[g * 2 + jl] + xv * w1c[g * 2 + jl];
    const float c = gate[0] * gate[2];          // f*0 + i*g
    c1s[jl][b] = c;
    const int j = j0 + jl;
    pub_store(&h1b[(size_t)(j >> 2) * (B * 4) + b * 4 + (j & 3)],
              gate[3] * tanhf(c));              // h1(0), parity 0
  }

  float4 H1[8], Q[8];
  int bar = 0;
  for (int t = 0; t < TT; ++t) {
    const float* h1cur = h1b + (t & 1) * HB;        // h1(t)
    float*       h1nxt = h1b + ((t + 1) & 1) * HB;  // h1(t+1)
    const float* h2old = h2b + ((t + 1) & 1) * HB;  // h2(t-1)
    float*       h2new = h2b + (t & 1) * HB;        // h2(t)

    // x prefetch for cell1(t+1) (cell1 runs on threads 128..255)
    float xvpref = 0.f;
    if (tid >= 128 && tid < 256 && t + 1 < SEQT)
      xvpref = xT[(size_t)(t + 1) * B + (tid & 63)];

    ++bar;
    gbar5(bb, wg, bar);   // publishes h1(t) (and h2(t-1) from last step)

    // non-defer fallback: duty WG computes out(t-1) inline from h2(t-1)
    if (!defer && wg == (t & 127) && t >= 1 && t <= SEQT - 1) {
      const float4* hb2 = (const float4*)h2old + (size_t)(wvu * 8) * B + lane;
      const float4* lw4 = (const float4*)lw + wvu * 8;
      float p = 0.f;
      #pragma unroll
      for (int i = 0; i < 8; ++i) {
        const float4 hv = hb2[i * B];
        const float4 wv = lw4[i];
        p = fmaf(wv.x, hv.x, p); p = fmaf(wv.y, hv.y, p);
        p = fmaf(wv.z, hv.z, p); p = fmaf(wv.w, hv.w, p);
      }
      outred[wvu][lane] = p;
      __syncthreads();
      if (tid < B) {
        float o = lbv;
        #pragma unroll
        for (int s = 0; s < NWAVE1; ++s) o += outred[s][tid];
        pub_store(&out[(size_t)tid * TT + (t - 1)], o);
      }
      __syncthreads();
    }

    // ---- merged dots: U1*h1(t) [next cell1] + W2*h1(t) + U2*h2(t-1) --------
    {
      const float4* p4 = (const float4*)h1cur + (size_t)(wvu * 8) * B + lane;
      const float4* q4 = (const float4*)h2old + (size_t)(wvu * 8) * B + lane;
      #pragma unroll
      for (int i = 0; i < 8; ++i) H1[i] = p4[i * B];
      #pragma unroll
      for (int i = 0; i < 8; ++i) Q[i] = q4[i * B];
      f2 a1[4], a2[4];
      #pragma unroll
      for (int r = 0; r < 4; ++r) { a1[r] = (f2){0.f, 0.f}; a2[r] = (f2){0.f, 0.f}; }
      #pragma unroll
      for (int c = 0; c < 8; ++c) {
        const float hh[4] = {H1[c].x, H1[c].y, H1[c].z, H1[c].w};
        const float qq[4] = {Q[c].x, Q[c].y, Q[c].z, Q[c].w};
        #pragma unroll
        for (int j = 0; j < 4; ++j) {
          const int k = c * 4 + j;
          const float4 u0 = *(const float4*)(wl1 + k * 8);        // b128
          const float4 u1 = *(const float4*)(wl1 + k * 8 + 4);    // b128
          const float4 w0 = *(const float4*)(wl2 + k * 16);       // b128
          const float4 w1 = *(const float4*)(wl2 + k * 16 + 4);   // b128
          const float4 w2 = *(const float4*)(wl2 + k * 16 + 8);   // b128
          const float4 w3 = *(const float4*)(wl2 + k * 16 + 12);  // b128
          const f2 h1s = {hh[j], hh[j]};
          const f2 h2s = {qq[j], qq[j]};
          a1[0] = __builtin_elementwise_fma((f2){u0.x, u0.y}, h1s, a1[0]);
          a1[1] = __builtin_elementwise_fma((f2){u0.z, u0.w}, h1s, a1[1]);
          a1[2] = __builtin_elementwise_fma((f2){u1.x, u1.y}, h1s, a1[2]);
          a1[3] = __builtin_elementwise_fma((f2){u1.z, u1.w}, h1s, a1[3]);
          a2[0] = __builtin_elementwise_fma((f2){w0.x, w0.y}, h1s, a2[0]);
          a2[1] = __builtin_elementwise_fma((f2){w0.z, w0.w}, h1s, a2[1]);
          a2[2] = __builtin_elementwise_fma((f2){w1.x, w1.y}, h1s, a2[2]);
          a2[3] = __builtin_elementwise_fma((f2){w1.z, w1.w}, h1s, a2[3]);
          a2[0] = __builtin_elementwise_fma((f2){w2.x, w2.y}, h2s, a2[0]);
          a2[1] = __builtin_elementwise_fma((f2){w2.z, w2.w}, h2s, a2[1]);
          a2[2] = __builtin_elementwise_fma((f2){w3.x, w3.y}, h2s, a2[2]);
          a2[3] = __builtin_elementwise_fma((f2){w3.z, w3.w}, h2s, a2[3]);
        }
      }
      #pragma unroll
      for (int r = 0; r < 4; ++r) {
        red[wvu][2 * r][lane]     = a2[r].x;   // rows 0-7: cell2 gates
        red[wvu][2 * r + 1][lane] = a2[r].y;
        red[wvu][8 + 2 * r][lane]     = a1[r].x;  // rows 8-15: next cell1
        red[wvu][8 + 2 * r + 1][lane] = a1[r].y;
      }
    }
    __syncthreads();

    // ---- cell2(t) on threads 0..127 ----------------------------------------
    if (tid < JPW * B) {
      const int jl = tid >> 6, b = tid & 63;
      float gate[4];
      #pragma unroll
      for (int g = 0; g < 4; ++g) {
        const int r = g * 2 + jl;
        float s = bs2[r];
        #pragma unroll
        for (int w = 0; w < NWAVE1; ++w) s += red[w][r][b];
        gate[g] = s;
      }
      const float c = gate[1] * c2s[jl][b] + gate[0] * gate[2];
      c2s[jl][b] = c;
      const float h2v = gate[3] * tanhf(c);
      const int j = j0 + jl;
      pub_store(&h2new[(size_t)(j >> 2) * (B * 4) + b * 4 + (j & 3)], h2v);
      if (defer && t < SEQT) pout[jl][b] = lwc[jl] * h2v;
    }
    // ---- cell1(t+1) (teacher) on threads 128..255, parallel with cell2 -----
    else if (tid < 2 * JPW * B && t + 1 < SEQT) {
      const int t2 = tid - JPW * B;
      const int jl = t2 >> 6, b = t2 & 63;
      float gate[4];
      #pragma unroll
      for (int g = 0; g < 4; ++g) {
        const int r = g * 2 + jl;
        float s = bs1[r] + xvpref * w1c[r];
        #pragma unroll
        for (int w = 0; w < NWAVE1; ++w) s += red[w][8 + r][b];
        gate[g] = s;
      }
      const float c = gate[1] * c1s[jl][b] + gate[0] * gate[2];
      c1s[jl][b] = c;
      const int j = j0 + jl;
      pub_store(&h1nxt[(size_t)(j >> 2) * (B * 4) + b * 4 + (j & 3)],
                gate[3] * tanhf(c));
    }
    __syncthreads();  // pout ready; red preserved for AR cell1

    // deferred-output partial store: 64 floats/WG/step
    if (defer && t < SEQT && tid < B) {
      pub_store(&part[((size_t)t * NWG + wg) * B + tid],
                pout[0][tid] + pout[1][tid]);
    }

    // ---- AR region: out(t) must be visible before cell1(t+1) ---------------
    if (t >= SEQT - 1) {
      ++bar;
      gbar5(bb, wg, bar);          // h2(t) visible
      if (wg == 0) {
        const float4* hb2 = (const float4*)h2new + (size_t)(wvu * 8) * B + lane;
        const float4* lw4 = (const float4*)lw + wvu * 8;
        float p = 0.f;
        #pragma unroll
        for (int i = 0; i < 8; ++i) {
          const float4 hv = hb2[i * B];
          const float4 wv = lw4[i];
          p = fmaf(wv.x, hv.x, p); p = fmaf(wv.y, hv.y, p);
          p = fmaf(wv.z, hv.z, p); p = fmaf(wv.w, hv.w, p);
        }
        outred[wvu][lane] = p;
        __syncthreads();
        if (tid < B) {
          float o = lbv;
          #pragma unroll
          for (int s = 0; s < NWAVE1; ++s) o += outred[s][tid];
          pub_store(&out[(size_t)tid * TT + t], o);
        }
        __syncthreads();
      }
      ++bar;
      gbar5(bb, wg, bar);          // out(t) visible
      if (t + 1 < TT && tid >= JPW * B && tid < 2 * JPW * B) {
        const int t2 = tid - JPW * B;
        const int jl = t2 >> 6, b = t2 & 63;
        const float xv = out[(size_t)b * TT + t];
        float gate[4];
        #pragma unroll
        for (int g = 0; g < 4; ++g) {
          const int r = g * 2 + jl;
          float s = bs1[r] + xv * w1c[r];
          #pragma unroll
          for (int w = 0; w < NWAVE1; ++w) s += red[w][8 + r][b];
          gate[g] = s;
        }
        const float c = gate[1] * c1s[jl][b] + gate[0] * gate[2];
        c1s[jl][b] = c;
        const int j = j0 + jl;
        pub_store(&h1nxt[(size_t)(j >> 2) * (B * 4) + b * 4 + (j & 3)],
                  gate[3] * tanhf(c));
      }
    }
  }

  // ---- defer mode tail: parallel reduction of output partials (t=0..1022) --
  if (defer) {
    ++bar;
    gbar5(bb, wg, bar);   // all partial stores visible + L2 inv'd
    for (int tt = wg; tt < SEQT - 1; tt += NWG) {
      const float* pp = part + ((size_t)tt * NWG + wvu * 16) * B + lane;
      float s = 0.f;
      #pragma unroll
      for (int i = 0; i < 16; ++i) s += pp[i * B];
      outred[wvu][lane] = s;
      __syncthreads();
      if (tid < B) {
        float o = lbv;
        #pragma unroll
        for (int v = 0; v < NWAVE1; ++v) o += outred[v][tid];
        out[(size_t)tid * TT + tt] = o;
      }
      __syncthreads();
    }
  }
}

// =================== fallback path (round-0 kernel, known correct) ===========
__device__ inline void gbar(int* cnt, int target) {
  __syncthreads();
  if (threadIdx.x == 0) {
    __threadfence();
    __hip_atomic_fetch_add(cnt, 1, __ATOMIC_RELEASE, __HIP_MEMORY_SCOPE_AGENT);
    while (__hip_atomic_load(cnt, __ATOMIC_ACQUIRE, __HIP_MEMORY_SCOPE_AGENT) < target) {
      __builtin_amdgcn_s_sleep(2);
    }
  }
  __syncthreads();
}

__global__ void __launch_bounds__(TPB) zero_ws(float* ws, int n) {
  int i = blockIdx.x * blockDim.x + threadIdx.x;
  if (i < n) ws[i] = 0.0f;
}

__global__ void __launch_bounds__(TPB) rnn_fallback(
    const float* __restrict__ x,
    const float* __restrict__ W1, const float* __restrict__ bW1,
    const float* __restrict__ U1, const float* __restrict__ bU1,
    const float* __restrict__ W2, const float* __restrict__ bW2,
    const float* __restrict__ U2, const float* __restrict__ bU2,
    const float* __restrict__ lw, const float* __restrict__ lb,
    float* out, float* ws)
{
  __shared__ float red[8][8][B];
  __shared__ float outred[8][B];
  __shared__ float c1s[JPW][B], c2s[JPW][B];
  __shared__ float w1c[8], bs1[8], bs2[8];

  int* cnt   = (int*)ws;
  float* h1b = ws + 16;
  float* h2b = h1b + 2 * HB;

  const int wg   = blockIdx.x;
  const int j0   = wg * JPW;
  const int tid  = threadIdx.x;
  const int lane = tid & 63;
  const int wvu  = __builtin_amdgcn_readfirstlane(tid >> 6);
  const int kb   = wvu << 6;

  if (tid < JPW * B) { c1s[tid >> 6][lane] = 0.f; c2s[tid >> 6][lane] = 0.f; }
  if (tid < 8) {
    const int g = tid >> 1, jl = tid & 1;
    const int row = g * HID + j0 + jl;
    w1c[tid] = W1[row];
    bs1[tid] = bW1[row] + bU1[row];
    bs2[tid] = bW2[row] + bU2[row];
  }
  __syncthreads();

  const float* u1p[8]; const float* w2p[8]; const float* u2p[8];
  #pragma unroll
  for (int r = 0; r < 8; ++r) {
    const int row = (r >> 1) * HID + j0 + (r & 1);
    u1p[r] = U1 + (size_t)row * HID + kb;
    w2p[r] = W2 + (size_t)row * HID + kb;
    u2p[r] = U2 + (size_t)row * HID + kb;
  }
  const float lbv = lb[0];

  int bar = 0;
  for (int t = 0; t < TT; ++t) {
    const float* h1old = h1b + ((t + 1) & 1) * HB;
    float*       h1new = h1b + (t & 1) * HB;
    const float* h2old = h2b + ((t + 1) & 1) * HB;
    float*       h2new = h2b + (t & 1) * HB;

    {
      const float* hp = h1old + (size_t)kb * B;
      float a0=0.f,a1=0.f,a2=0.f,a3=0.f,a4=0.f,a5=0.f,a6=0.f,a7=0.f;
      #pragma unroll 8
      for (int k = 0; k < 64; ++k) {
        const float hv = hp[k * B + lane];
        a0 = fmaf(u1p[0][k], hv, a0); a1 = fmaf(u1p[1][k], hv, a1);
        a2 = fmaf(u1p[2][k], hv, a2); a3 = fmaf(u1p[3][k], hv, a3);
        a4 = fmaf(u1p[4][k], hv, a4); a5 = fmaf(u1p[5][k], hv, a5);
        a6 = fmaf(u1p[6][k], hv, a6); a7 = fmaf(u1p[7][k], hv, a7);
      }
      red[wvu][0][lane]=a0; red[wvu][1][lane]=a1; red[wvu][2][lane]=a2; red[wvu][3][lane]=a3;
      red[wvu][4][lane]=a4; red[wvu][5][lane]=a5; red[wvu][6][lane]=a6; red[wvu][7][lane]=a7;
    }
    __syncthreads();

    if (tid < JPW * B) {
      const int jl = tid >> 6, b = tid & 63;
      const float xv = (t < SEQT) ? x[(size_t)b * SEQT + t]
                                  : out[(size_t)b * TT + (t - 1)];
      float gate[4];
      #pragma unroll
      for (int g = 0; g < 4; ++g) {
        const int r = g * 2 + jl;
        float s = bs1[r] + xv * w1c[r];
        #pragma unroll
        for (int w = 0; w < 8; ++w) s += red[w][r][b];
        gate[g] = s;
      }
      const float c = gate[1] * c1s[jl][b] + gate[0] * gate[2];
      c1s[jl][b] = c;
      h1new[(size_t)(j0 + jl) * B + b] = gate[3] * tanhf(c);
    }

    ++bar;
    gbar(cnt, NWG * bar);

    if (wg == 0 && t >= 1 && t <= SEQT - 1) {
      const float* hb2 = h2old + (size_t)(wvu * 64) * B;
      const float* lwp = lw + wvu * 64;
      float p = 0.f;
      #pragma unroll 8
      for (int j = 0; j < 64; ++j) p = fmaf(lwp[j], hb2[j * B + lane], p);
      outred[wvu][lane] = p;
      __syncthreads();
      if (tid < B) {
        float o = lbv;
        #pragma unroll
        for (int s = 0; s < 8; ++s) o += outred[s][tid];
        out[(size_t)tid * TT + (t - 1)] = o;
      }
      __syncthreads();
    }

    {
      const float* h1p = h1new + (size_t)kb * B;
      const float* h2p = h2old + (size_t)kb * B;
      float s0=0.f,s1=0.f,s2=0.f,s3=0.f,s4=0.f,s5=0.f,s6=0.f,s7=0.f;
      float q0=0.f,q1=0.f,q2=0.f,q3=0.f,q4=0.f,q5=0.f,q6=0.f,q7=0.f;
      #pragma unroll 4
      for (int k = 0; k < 64; ++k) {
        const float h1v = h1p[k * B + lane];
        const float h2v = h2p[k * B + lane];
        s0 = fmaf(w2p[0][k], h1v, s0); q0 = fmaf(u2p[0][k], h2v, q0);
        s1 = fmaf(w2p[1][k], h1v, s1); q1 = fmaf(u2p[1][k], h2v, q1);
        s2 = fmaf(w2p[2][k], h1v, s2); q2 = fmaf(u2p[2][k], h2v, q2);
        s3 = fmaf(w2p[3][k], h1v, s3); q3 = fmaf(u2p[3][k], h2v, q3);
        s4 = fmaf(w2p[4][k], h1v, s4); q4 = fmaf(u2p[4][k], h2v, q4);
        s5 = fmaf(w2p[5][k], h1v, s5); q5 = fmaf(u2p[5][k], h2v, q5);
        s6 = fmaf(w2p[6][k], h1v, s6); q6 = fmaf(u2p[6][k], h2v, q6);
        s7 = fmaf(w2p[7][k], h1v, s7); q7 = fmaf(u2p[7][k], h2v, q7);
      }
      red[wvu][0][lane]=s0+q0; red[wvu][1][lane]=s1+q1;
      red[wvu][2][lane]=s2+q2; red[wvu][3][lane]=s3+q3;
      red[wvu][4][lane]=s4+q4; red[wvu][5][lane]=s5+q5;
      red[wvu][6][lane]=s6+q6; red[wvu][7][lane]=s7+q7;
    }
    __syncthreads();

    if (tid < JPW * B) {
      const int jl = tid >> 6, b = tid & 63;
      float gate[4];
      #pragma unroll
      for (int g = 0; g < 4; ++g) {
        const int r = g * 2 + jl;
        float s = bs2[r];
        #pragma unroll
        for (int w = 0; w < 8; ++w) s += red[w][r][b];
        gate[g] = s;
      }
      const float c = gate[1] * c2s[jl][b] + gate[0] * gate[2];
      c2s[jl][b] = c;
      h2new[(size_t)(j0 + jl) * B + b] = gate[3] * tanhf(c);
    }
    __syncthreads();

    if (t >= SEQT - 1) {
      ++bar;
      gbar(cnt, NWG * bar);
      if (wg == 0) {
        const float* hb2 = h2new + (size_t)(wvu * 64) * B;
        const float* lwp = lw + wvu * 64;
        float p = 0.f;
        #pragma unroll 8
        for (int j = 0; j < 64; ++j) p = fmaf(lwp[j], hb2[j * B + lane], p);
        outred[wvu][lane] = p;
        __syncthreads();
        if (tid < B) {
          float o = lbv;
          #pragma unroll
          for (int s = 0; s < 8; ++s) o += outred[s][tid];
          out[(size_t)tid * TT + t] = o;
        }
        __syncthreads();
      }
      ++bar;
      gbar(cnt, NWG * bar);
    }
  }
}

extern "C" void kernel_launch(void* const* d_in, const int* in_sizes, int n_in,
                              void* d_out, int out_size, void* d_ws, size_t ws_size,
                              hipStream_t stream) {
  (void)in_sizes; (void)n_in; (void)out_size;
  const float* x   = (const float*)d_in[0];
  const float* W1  = (const float*)d_in[1];
  const float* bW1 = (const float*)d_in[2];
  const float* U1  = (const float*)d_in[3];
  const float* bU1 = (const float*)d_in[4];
  const float* W2  = (const float*)d_in[5];
  const float* bW2 = (const float*)d_in[6];
  const float* U2  = (const float*)d_in[7];
  const float* bU2 = (const float*)d_in[8];
  const float* lw  = (const float*)d_in[9];
  const float* lb  = (const float*)d_in[10];

  float* out = (float*)d_out;
  float* ws  = (float*)d_ws;

  if (ws_size >= (size_t)WS_TOT_F * sizeof(float)) {
    const int defer = (ws_size >= WS_TOT2_F * sizeof(float)) ? 1 : 0;
    prep_ws<<<(WS_TOT_F + 255) / 256, 256, 0, stream>>>(x, U1, W2, U2, ws);
    rnn_main<<<NWG, TPB1, 0, stream>>>(W1, bW1, bU1, bW2, bU2, lw, lb, out,
                                       (int*)ws, ws + WS_H1_F, ws + WS_H2_F,
                                       ws + WS_BLOB_F, ws + WS_XT_F,
                                       ws + WS_PART_F, defer);
  } else {
    const int nzero = 16 + 4 * HID * B;
    zero_ws<<<(nzero + TPB - 1) / TPB, TPB, 0, stream>>>(ws, nzero);
    rnn_fallback<<<NWG, TPB, 0, stream>>>(x, W1, bW1, U1, bU1,
                                          W2, bW2, U2, bU2, lw, lb, out, ws);
  }
}

// Round 13
// 11670.455 us; speedup vs baseline: 1.3291x; 1.1301x over previous
//
#include <hip/hip_runtime.h>
#include <math.h>

#define HID 512
#define B 64
#define SEQT 1024
#define FUT 16
#define TT (SEQT + FUT)
#define NWG 256
#define TPB 512          // fallback path block size
#define TPB1 1024        // main kernel block size (16 waves, 4/SIMD)
#define NWAVE1 16
#define JPW 2            // hidden units owned per WG = HID/NWG
#define HB (HID * B)     // one h buffer, floats
#define BLOBF 12288      // floats per WG: 4096 (phase1) + 8192 (phase2)

typedef __attribute__((ext_vector_type(2))) float f2;   // v_pk_fma_f32 pairs

// ws float layout (main path):
//   [0..511]               barrier block (ints): slot[wg] at int wg (wg<256)
//   [512 .. +2HB)          h1 double buffer  (float4 tiles: h4[k>>2][b][k&3])
//   [.. +2HB)              h2 double buffer  (same layout)
//   [.. +NWG*BLOBF)        rearranged weight blobs (per WG)
//   [.. +SEQT*B)           xT (x transposed to [t][b])
//   [.. +SEQT*NWG*B)       deferred-output partials part[t][wg][b] (defer mode)
#define WS_H1_F   512
#define WS_H2_F   (WS_H1_F + 2 * HB)
#define WS_BLOB_F (WS_H2_F + 2 * HB)
#define WS_XT_F   (WS_BLOB_F + NWG * BLOBF)
#define WS_TOT_F  (WS_XT_F + SEQT * B)
#define WS_PART_F WS_TOT_F
#define WS_TOT2_F (WS_PART_F + (size_t)SEQT * NWG * B)

// r13 single-variable change: publish via atomic EXCHANGE (RMW executes at
// the coherence point and ALLOCATES there), not write-through store (which is
// memory-side no-allocate -> h round-tripped HBM every step; FETCH_SIZE
// showed ~1.1 MB/step of HBM h re-reads in r6-r12).
__device__ inline void pub_store(float* p, float v) {
  (void)__hip_atomic_exchange(p, v, __ATOMIC_RELAXED, __HIP_MEMORY_SCOPE_AGENT);
}

// ---- grid barrier v5 (r8): slot stores + every WG polls all 256 slots ------
// Rules from r2-r10: no RMW on the ARRIVAL slots (contended line); relaxed
// spin loads (acquire-per-poll = buffer_inv per poll = L2 dead); ONE pre-spin
// acquire fence (inv) per WG per barrier.
__device__ inline void gbar5(int* bb, int wg, int bar) {
  __builtin_amdgcn_s_waitcnt(0);   // all threads drain own publishes
  __syncthreads();
  const int tid = threadIdx.x;
  if (tid == 0) {
    __hip_atomic_store(bb + wg, bar, __ATOMIC_RELAXED, __HIP_MEMORY_SCOPE_AGENT);
    __builtin_amdgcn_fence(__ATOMIC_ACQUIRE, "agent");  // pre-spin inv, once
  }
  if (tid < 64) {
    for (;;) {
      int a = __hip_atomic_load(bb + tid,       __ATOMIC_RELAXED, __HIP_MEMORY_SCOPE_AGENT);
      int b = __hip_atomic_load(bb + 64  + tid, __ATOMIC_RELAXED, __HIP_MEMORY_SCOPE_AGENT);
      int c = __hip_atomic_load(bb + 128 + tid, __ATOMIC_RELAXED, __HIP_MEMORY_SCOPE_AGENT);
      int d = __hip_atomic_load(bb + 192 + tid, __ATOMIC_RELAXED, __HIP_MEMORY_SCOPE_AGENT);
      if (__all(a >= bar && b >= bar && c >= bar && d >= bar)) break;
      __builtin_amdgcn_s_sleep(1);
    }
  }
  __syncthreads();  // h loads below stay below
}

// ---------------- prep: zero state, rearrange weights, transpose x -----------
__global__ void __launch_bounds__(256) prep_ws(
    const float* __restrict__ x,
    const float* __restrict__ U1, const float* __restrict__ W2,
    const float* __restrict__ U2, float* __restrict__ ws)
{
  const int idx = blockIdx.x * blockDim.x + threadIdx.x;
  if (idx < WS_BLOB_F) ws[idx] = 0.0f;         // barrier + h buffers
  {
    const int i2 = idx - WS_BLOB_F;
    if (i2 >= 0 && i2 < NWG * BLOBF) {
      const int wg  = i2 / BLOBF;
      const int off = i2 - wg * BLOBF;
      const int j0  = wg * JPW;
      float v;
      if (off < 4096) {                        // phase1: [k*8 + r] = U1[row(r)][k]
        const int k = off >> 3, r = off & 7;
        const int row = (r >> 1) * HID + j0 + (r & 1);
        v = U1[(size_t)row * HID + k];
      } else {                                 // phase2: [k*16 + rr]
        const int o2 = off - 4096;
        const int k = o2 >> 4, rr = o2 & 15;
        const int r = rr & 7;
        const int row = (r >> 1) * HID + j0 + (r & 1);
        v = (rr < 8) ? W2[(size_t)row * HID + k] : U2[(size_t)row * HID + k];
      }
      ws[WS_BLOB_F + i2] = v;
    }
  }
  {
    const int i3 = idx - WS_XT_F;
    if (i3 >= 0 && i3 < SEQT * B) {
      const int t = i3 >> 6, b = i3 & 63;
      ws[WS_XT_F + i3] = x[(size_t)b * SEQT + t];
    }
  }
}

// -------- persistent 2-layer LSTM: r10 structure + atomicExch publish --------
// 16 waves/WG (4/SIMD). Wave wvu owns k-chunk [wvu*32, wvu*32+32).
// phase1 uses H1 registers (h1(t-1), carried from last step's phase2 load) ->
// NO global loads before the barrier. phase2 loads H1<-h1(t), Q<-h2(t-1).
__global__ void __launch_bounds__(TPB1, 1) rnn_main(
    const float* __restrict__ W1, const float* __restrict__ bW1,
    const float* __restrict__ bU1,
    const float* __restrict__ bW2, const float* __restrict__ bU2,
    const float* __restrict__ lw, const float* __restrict__ lb,
    float* __restrict__ out,
    int* __restrict__ bb,
    float* __restrict__ h1b, float* __restrict__ h2b,
    const float* __restrict__ wbl, const float* __restrict__ xT,
    float* __restrict__ part, int defer)
{
  __shared__ float wlds[BLOBF];         // 48 KB persistent weight blob
  __shared__ float red[NWAVE1][8][B];   // per-wave partial dots, 32 KB
  __shared__ float outred[NWAVE1][B];   // output-head reduction, 4 KB
  __shared__ float c1s[JPW][B], c2s[JPW][B];
  __shared__ float pout[JPW][B];        // per-step output partial staging
  __shared__ float w1c[8], bs1[8], bs2[8], lwc[JPW];

  const int wg   = blockIdx.x;
  const int j0   = wg * JPW;
  const int tid  = threadIdx.x;
  const int lane = tid & 63;
  const int wvu  = __builtin_amdgcn_readfirstlane(tid >> 6);

  // ---- one-time: copy this WG's weight blob into LDS ----
  {
    const float4* gsrc = (const float4*)(wbl + (size_t)wg * BLOBF);
    float4* ldst = (float4*)wlds;
    #pragma unroll
    for (int i = 0; i < BLOBF / 4 / TPB1; ++i)
      ldst[i * TPB1 + tid] = gsrc[i * TPB1 + tid];
  }
  if (tid < JPW * B) { c1s[tid >> 6][lane] = 0.f; c2s[tid >> 6][lane] = 0.f; }
  if (tid < 8) {
    const int g = tid >> 1, jl = tid & 1;
    const int row = g * HID + j0 + jl;
    w1c[tid] = W1[row];
    bs1[tid] = bW1[row] + bU1[row];
    bs2[tid] = bW2[row] + bU2[row];
  }
  if (tid < JPW) lwc[tid] = lw[j0 + tid];
  __syncthreads();

  const float* wl1 = wlds + wvu * 256;          // phase1 weights, this wave
  const float* wl2 = wlds + 4096 + wvu * 512;   // phase2 weights, this wave
  const float lbv = lb[0];

  float4 H1[8], Q[8];                           // h1 carry + h2old staging
  #pragma unroll
  for (int i = 0; i < 8; ++i) H1[i] = make_float4(0.f, 0.f, 0.f, 0.f);

  int bar = 0;
  for (int t = 0; t < TT; ++t) {
    float*       h1new = h1b + (t & 1) * HB;
    const float* h2old = h2b + ((t + 1) & 1) * HB;
    float*       h2new = h2b + (t & 1) * HB;

    // prefetch x for cell-1 (teacher region)
    float xvpref = 0.f;
    if (tid < JPW * B && t < SEQT) xvpref = xT[(size_t)t * B + lane];

    // -------- phase 1: gates1 = U1 h1(t-1), h1(t-1) in H1 registers ---------
    {
      f2 a01 = {0.f, 0.f}, a23 = {0.f, 0.f}, a45 = {0.f, 0.f}, a67 = {0.f, 0.f};
      #pragma unroll
      for (int c = 0; c < 8; ++c) {             // 8 k-quads in this wave's 32-k
        const float hh[4] = {H1[c].x, H1[c].y, H1[c].z, H1[c].w};
        #pragma unroll
        for (int j = 0; j < 4; ++j) {
          const float4 wA = *(const float4*)(wl1 + c * 32 + j * 8);      // b128
          const float4 wB = *(const float4*)(wl1 + c * 32 + j * 8 + 4);  // b128
          const f2 hs = {hh[j], hh[j]};
          const f2 wA0 = {wA.x, wA.y}, wA1 = {wA.z, wA.w};
          const f2 wB0 = {wB.x, wB.y}, wB1 = {wB.z, wB.w};
          a01 = __builtin_elementwise_fma(wA0, hs, a01);
          a23 = __builtin_elementwise_fma(wA1, hs, a23);
          a45 = __builtin_elementwise_fma(wB0, hs, a45);
          a67 = __builtin_elementwise_fma(wB1, hs, a67);
        }
      }
      red[wvu][0][lane] = a01.x; red[wvu][1][lane] = a01.y;
      red[wvu][2][lane] = a23.x; red[wvu][3][lane] = a23.y;
      red[wvu][4][lane] = a45.x; red[wvu][5][lane] = a45.y;
      red[wvu][6][lane] = a67.x; red[wvu][7][lane] = a67.y;
    }
    __syncthreads();

    // cell-1 elementwise (2 j's x 64 b = 128 threads)
    if (tid < JPW * B) {
      const int jl = tid >> 6, b = tid & 63;
      const float xv = (t < SEQT) ? xvpref : out[(size_t)b * TT + (t - 1)];
      float gate[4];
      #pragma unroll
      for (int g = 0; g < 4; ++g) {
        const int r = g * 2 + jl;
        float s = bs1[r] + xv * w1c[r];
        #pragma unroll
        for (int w = 0; w < NWAVE1; ++w) s += red[w][r][b];
        gate[g] = s;
      }
      const float c = gate[1] * c1s[jl][b] + gate[0] * gate[2];
      c1s[jl][b] = c;
      const int j = j0 + jl;
      pub_store(&h1new[(size_t)(j >> 2) * (B * 4) + b * 4 + (j & 3)],
                gate[3] * tanhf(c));
    }

    ++bar;
    gbar5(bb, wg, bar);

    // non-defer mode only: duty WG computes output head inline
    if (!defer && wg == (t & 127) && t >= 1 && t <= SEQT - 1) {
      const float4* hb2 = (const float4*)h2old + (size_t)(wvu * 8) * B + lane;
      const float4* lw4 = (const float4*)lw + wvu * 8;
      float p = 0.f;
      #pragma unroll
      for (int i = 0; i < 8; ++i) {
        const float4 hv = hb2[i * B];
        const float4 wv = lw4[i];
        p = fmaf(wv.x, hv.x, p); p = fmaf(wv.y, hv.y, p);
        p = fmaf(wv.z, hv.z, p); p = fmaf(wv.w, hv.w, p);
      }
      outred[wvu][lane] = p;
      __syncthreads();
      if (tid < B) {
        float o = lbv;
        #pragma unroll
        for (int s = 0; s < NWAVE1; ++s) o += outred[s][tid];
        pub_store(&out[(size_t)tid * TT + (t - 1)], o);
      }
      __syncthreads();
    }

    // -------- phase 2: gates2 = W2 h1(t) + U2 h2(t-1) ------------------------
    // H1 <- h1(t) (kept for next step's phase 1), Q <- h2(t-1)
    {
      const float4* pp4 = (const float4*)h1new + (size_t)(wvu * 8) * B + lane;
      const float4* qq4 = (const float4*)h2old + (size_t)(wvu * 8) * B + lane;
      #pragma unroll
      for (int i = 0; i < 8; ++i) H1[i] = pp4[i * B];
      #pragma unroll
      for (int i = 0; i < 8; ++i) Q[i] = qq4[i * B];
      f2 a01 = {0.f, 0.f}, a23 = {0.f, 0.f}, a45 = {0.f, 0.f}, a67 = {0.f, 0.f};
      #pragma unroll
      for (int c = 0; c < 8; ++c) {
        const float hp_[4] = {H1[c].x, H1[c].y, H1[c].z, H1[c].w};
        const float hq_[4] = {Q[c].x, Q[c].y, Q[c].z, Q[c].w};
        #pragma unroll
        for (int j = 0; j < 4; ++j) {
          const float4 w0 = *(const float4*)(wl2 + c * 64 + j * 16);       // b128
          const float4 w1 = *(const float4*)(wl2 + c * 64 + j * 16 + 4);   // b128
          const float4 w2 = *(const float4*)(wl2 + c * 64 + j * 16 + 8);   // b128
          const float4 w3 = *(const float4*)(wl2 + c * 64 + j * 16 + 12);  // b128
          const f2 hs1 = {hp_[j], hp_[j]};
          const f2 hs2 = {hq_[j], hq_[j]};
          const f2 w0a = {w0.x, w0.y}, w0b = {w0.z, w0.w};
          const f2 w1a = {w1.x, w1.y}, w1b = {w1.z, w1.w};
          const f2 w2a = {w2.x, w2.y}, w2b = {w2.z, w2.w};
          const f2 w3a = {w3.x, w3.y}, w3b = {w3.z, w3.w};
          a01 = __builtin_elementwise_fma(w0a, hs1, a01);
          a23 = __builtin_elementwise_fma(w0b, hs1, a23);
          a45 = __builtin_elementwise_fma(w1a, hs1, a45);
          a67 = __builtin_elementwise_fma(w1b, hs1, a67);
          a01 = __builtin_elementwise_fma(w2a, hs2, a01);
          a23 = __builtin_elementwise_fma(w2b, hs2, a23);
          a45 = __builtin_elementwise_fma(w3a, hs2, a45);
          a67 = __builtin_elementwise_fma(w3b, hs2, a67);
        }
      }
      red[wvu][0][lane] = a01.x; red[wvu][1][lane] = a01.y;
      red[wvu][2][lane] = a23.x; red[wvu][3][lane] = a23.y;
      red[wvu][4][lane] = a45.x; red[wvu][5][lane] = a45.y;
      red[wvu][6][lane] = a67.x; red[wvu][7][lane] = a67.y;
    }
    __syncthreads();

    // cell-2 elementwise
    if (tid < JPW * B) {
      const int jl = tid >> 6, b = tid & 63;
      float gate[4];
      #pragma unroll
      for (int g = 0; g < 4; ++g) {
        const int r = g * 2 + jl;
        float s = bs2[r];
        #pragma unroll
        for (int w = 0; w < NWAVE1; ++w) s += red[w][r][b];
        gate[g] = s;
      }
      const float c = gate[1] * c2s[jl][b] + gate[0] * gate[2];
      c2s[jl][b] = c;
      const float h2v = gate[3] * tanhf(c);
      const int j = j0 + jl;
      pub_store(&h2new[(size_t)(j >> 2) * (B * 4) + b * 4 + (j & 3)], h2v);
      if (defer && t < SEQT) pout[jl][b] = lwc[jl] * h2v;  // output partial
    }
    __syncthreads();  // protect red[] + publish pout

    // deferred-output partial store: 64 floats/WG/step
    if (defer && t < SEQT && tid < B) {
      pub_store(&part[((size_t)t * NWG + wg) * B + tid],
                pout[0][tid] + pout[1][tid]);
    }

    // Autoregressive region: out(t) must be visible before phase1(t+1)
    if (t >= SEQT - 1) {
      ++bar;
      gbar5(bb, wg, bar);
      if (wg == 0) {
        const float4* hb2 = (const float4*)h2new + (size_t)(wvu * 8) * B + lane;
        const float4* lw4 = (const float4*)lw + wvu * 8;
        float p = 0.f;
        #pragma unroll
        for (int i = 0; i < 8; ++i) {
          const float4 hv = hb2[i * B];
          const float4 wv = lw4[i];
          p = fmaf(wv.x, hv.x, p); p = fmaf(wv.y, hv.y, p);
          p = fmaf(wv.z, hv.z, p); p = fmaf(wv.w, hv.w, p);
        }
        outred[wvu][lane] = p;
        __syncthreads();
        if (tid < B) {
          float o = lbv;
          #pragma unroll
          for (int s = 0; s < NWAVE1; ++s) o += outred[s][tid];
          pub_store(&out[(size_t)tid * TT + t], o);
        }
        __syncthreads();
      }
      ++bar;
      gbar5(bb, wg, bar);
    }
  }

  // ---- defer mode tail: parallel reduction of output partials (t=0..1022) --
  if (defer) {
    ++bar;
    gbar5(bb, wg, bar);   // all partial stores visible + L2 inv'd
    for (int tt = wg; tt < SEQT - 1; tt += NWG) {
      const float* pp = part + ((size_t)tt * NWG + wvu * 16) * B + lane;
      float s = 0.f;
      #pragma unroll
      for (int i = 0; i < 16; ++i) s += pp[i * B];
      outred[wvu][lane] = s;
      __syncthreads();
      if (tid < B) {
        float o = lbv;
        #pragma unroll
        for (int v = 0; v < NWAVE1; ++v) o += outred[v][tid];
        out[(size_t)tid * TT + tt] = o;
      }
      __syncthreads();
    }
  }
}

// =================== fallback path (round-0 kernel, known correct) ===========
__device__ inline void gbar(int* cnt, int target) {
  __syncthreads();
  if (threadIdx.x == 0) {
    __threadfence();
    __hip_atomic_fetch_add(cnt, 1, __ATOMIC_RELEASE, __HIP_MEMORY_SCOPE_AGENT);
    while (__hip_atomic_load(cnt, __ATOMIC_ACQUIRE, __HIP_MEMORY_SCOPE_AGENT) < target) {
      __builtin_amdgcn_s_sleep(2);
    }
  }
  __syncthreads();
}

__global__ void __launch_bounds__(TPB) zero_ws(float* ws, int n) {
  int i = blockIdx.x * blockDim.x + threadIdx.x;
  if (i < n) ws[i] = 0.0f;
}

__global__ void __launch_bounds__(TPB) rnn_fallback(
    const float* __restrict__ x,
    const float* __restrict__ W1, const float* __restrict__ bW1,
    const float* __restrict__ U1, const float* __restrict__ bU1,
    const float* __restrict__ W2, const float* __restrict__ bW2,
    const float* __restrict__ U2, const float* __restrict__ bU2,
    const float* __restrict__ lw, const float* __restrict__ lb,
    float* out, float* ws)
{
  __shared__ float red[8][8][B];
  __shared__ float outred[8][B];
  __shared__ float c1s[JPW][B], c2s[JPW][B];
  __shared__ float w1c[8], bs1[8], bs2[8];

  int* cnt   = (int*)ws;
  float* h1b = ws + 16;
  float* h2b = h1b + 2 * HB;

  const int wg   = blockIdx.x;
  const int j0   = wg * JPW;
  const int tid  = threadIdx.x;
  const int lane = tid & 63;
  const int wvu  = __builtin_amdgcn_readfirstlane(tid >> 6);
  const int kb   = wvu << 6;

  if (tid < JPW * B) { c1s[tid >> 6][lane] = 0.f; c2s[tid >> 6][lane] = 0.f; }
  if (tid < 8) {
    const int g = tid >> 1, jl = tid & 1;
    const int row = g * HID + j0 + jl;
    w1c[tid] = W1[row];
    bs1[tid] = bW1[row] + bU1[row];
    bs2[tid] = bW2[row] + bU2[row];
  }
  __syncthreads();

  const float* u1p[8]; const float* w2p[8]; const float* u2p[8];
  #pragma unroll
  for (int r = 0; r < 8; ++r) {
    const int row = (r >> 1) * HID + j0 + (r & 1);
    u1p[r] = U1 + (size_t)row * HID + kb;
    w2p[r] = W2 + (size_t)row * HID + kb;
    u2p[r] = U2 + (size_t)row * HID + kb;
  }
  const float lbv = lb[0];

  int bar = 0;
  for (int t = 0; t < TT; ++t) {
    const float* h1old = h1b + ((t + 1) & 1) * HB;
    float*       h1new = h1b + (t & 1) * HB;
    const float* h2old = h2b + ((t + 1) & 1) * HB;
    float*       h2new = h2b + (t & 1) * HB;

    {
      const float* hp = h1old + (size_t)kb * B;
      float a0=0.f,a1=0.f,a2=0.f,a3=0.f,a4=0.f,a5=0.f,a6=0.f,a7=0.f;
      #pragma unroll 8
      for (int k = 0; k < 64; ++k) {
        const float hv = hp[k * B + lane];
        a0 = fmaf(u1p[0][k], hv, a0); a1 = fmaf(u1p[1][k], hv, a1);
        a2 = fmaf(u1p[2][k], hv, a2); a3 = fmaf(u1p[3][k], hv, a3);
        a4 = fmaf(u1p[4][k], hv, a4); a5 = fmaf(u1p[5][k], hv, a5);
        a6 = fmaf(u1p[6][k], hv, a6); a7 = fmaf(u1p[7][k], hv, a7);
      }
      red[wvu][0][lane]=a0; red[wvu][1][lane]=a1; red[wvu][2][lane]=a2; red[wvu][3][lane]=a3;
      red[wvu][4][lane]=a4; red[wvu][5][lane]=a5; red[wvu][6][lane]=a6; red[wvu][7][lane]=a7;
    }
    __syncthreads();

    if (tid < JPW * B) {
      const int jl = tid >> 6, b = tid & 63;
      const float xv = (t < SEQT) ? x[(size_t)b * SEQT + t]
                                  : out[(size_t)b * TT + (t - 1)];
      float gate[4];
      #pragma unroll
      for (int g = 0; g < 4; ++g) {
        const int r = g * 2 + jl;
        float s = bs1[r] + xv * w1c[r];
        #pragma unroll
        for (int w = 0; w < 8; ++w) s += red[w][r][b];
        gate[g] = s;
      }
      const float c = gate[1] * c1s[jl][b] + gate[0] * gate[2];
      c1s[jl][b] = c;
      h1new[(size_t)(j0 + jl) * B + b] = gate[3] * tanhf(c);
    }

    ++bar;
    gbar(cnt, NWG * bar);

    if (wg == 0 && t >= 1 && t <= SEQT - 1) {
      const float* hb2 = h2old + (size_t)(wvu * 64) * B;
      const float* lwp = lw + wvu * 64;
      float p = 0.f;
      #pragma unroll 8
      for (int j = 0; j < 64; ++j) p = fmaf(lwp[j], hb2[j * B + lane], p);
      outred[wvu][lane] = p;
      __syncthreads();
      if (tid < B) {
        float o = lbv;
        #pragma unroll
        for (int s = 0; s < 8; ++s) o += outred[s][tid];
        out[(size_t)tid * TT + (t - 1)] = o;
      }
      __syncthreads();
    }

    {
      const float* h1p = h1new + (size_t)kb * B;
      const float* h2p = h2old + (size_t)kb * B;
      float s0=0.f,s1=0.f,s2=0.f,s3=0.f,s4=0.f,s5=0.f,s6=0.f,s7=0.f;
      float q0=0.f,q1=0.f,q2=0.f,q3=0.f,q4=0.f,q5=0.f,q6=0.f,q7=0.f;
      #pragma unroll 4
      for (int k = 0; k < 64; ++k) {
        const float h1v = h1p[k * B + lane];
        const float h2v = h2p[k * B + lane];
        s0 = fmaf(w2p[0][k], h1v, s0); q0 = fmaf(u2p[0][k], h2v, q0);
        s1 = fmaf(w2p[1][k], h1v, s1); q1 = fmaf(u2p[1][k], h2v, q1);
        s2 = fmaf(w2p[2][k], h1v, s2); q2 = fmaf(u2p[2][k], h2v, q2);
        s3 = fmaf(w2p[3][k], h1v, s3); q3 = fmaf(u2p[3][k], h2v, q3);
        s4 = fmaf(w2p[4][k], h1v, s4); q4 = fmaf(u2p[4][k], h2v, q4);
        s5 = fmaf(w2p[5][k], h1v, s5); q5 = fmaf(u2p[5][k], h2v, q5);
        s6 = fmaf(w2p[6][k], h1v, s6); q6 = fmaf(u2p[6][k], h2v, q6);
        s7 = fmaf(w2p[7][k], h1v, s7); q7 = fmaf(u2p[7][k], h2v, q7);
      }
      red[wvu][0][lane]=s0+q0; red[wvu][1][lane]=s1+q1;
      red[wvu][2][lane]=s2+q2; red[wvu][3][lane]=s3+q3;
      red[wvu][4][lane]=s4+q4; red[wvu][5][lane]=s5+q5;
      red[wvu][6][lane]=s6+q6; red[wvu][7][lane]=s7+q7;
    }
    __syncthreads();

    if (tid < JPW * B) {
      const int jl = tid >> 6, b = tid & 63;
      float gate[4];
      #pragma unroll
      for (int g = 0; g < 4; ++g) {
        const int r = g * 2 + jl;
        float s = bs2[r];
        #pragma unroll
        for (int w = 0; w < 8; ++w) s += red[w][r][b];
        gate[g] = s;
      }
      const float c = gate[1] * c2s[jl][b] + gate[0] * gate[2];
      c2s[jl][b] = c;
      h2new[(size_t)(j0 + jl) * B + b] = gate[3] * tanhf(c);
    }
    __syncthreads();

    if (t >= SEQT - 1) {
      ++bar;
      gbar(cnt, NWG * bar);
      if (wg == 0) {
        const float* hb2 = h2new + (size_t)(wvu * 64) * B;
        const float* lwp = lw + wvu * 64;
        float p = 0.f;
        #pragma unroll 8
        for (int j = 0; j < 64; ++j) p = fmaf(lwp[j], hb2[j * B + lane], p);
        outred[wvu][lane] = p;
        __syncthreads();
        if (tid < B) {
          float o = lbv;
          #pragma unroll
          for (int s = 0; s < 8; ++s) o += outred[s][tid];
          out[(size_t)tid * TT + t] = o;
        }
        __syncthreads();
      }
      ++bar;
      gbar(cnt, NWG * bar);
    }
  }
}

extern "C" void kernel_launch(void* const* d_in, const int* in_sizes, int n_in,
                              void* d_out, int out_size, void* d_ws, size_t ws_size,
                              hipStream_t stream) {
  (void)in_sizes; (void)n_in; (void)out_size;
  const float* x   = (const float*)d_in[0];
  const float* W1  = (const float*)d_in[1];
  const float* bW1 = (const float*)d_in[2];
  const float* U1  = (const float*)d_in[3];
  const float* bU1 = (const float*)d_in[4];
  const float* W2  = (const float*)d_in[5];
  const float* bW2 = (const float*)d_in[6];
  const float* U2  = (const float*)d_in[7];
  const float* bU2 = (const float*)d_in[8];
  const float* lw  = (const float*)d_in[9];
  const float* lb  = (const float*)d_in[10];

  float* out = (float*)d_out;
  float* ws  = (float*)d_ws;

  if (ws_size >= (size_t)WS_TOT_F * sizeof(float)) {
    const int defer = (ws_size >= WS_TOT2_F * sizeof(float)) ? 1 : 0;
    prep_ws<<<(WS_TOT_F + 255) / 256, 256, 0, stream>>>(x, U1, W2, U2, ws);
    rnn_main<<<NWG, TPB1, 0, stream>>>(W1, bW1, bU1, bW2, bU2, lw, lb, out,
                                       (int*)ws, ws + WS_H1_F, ws + WS_H2_F,
                                       ws + WS_BLOB_F, ws + WS_XT_F,
                                       ws + WS_PART_F, defer);
  } else {
    const int nzero = 16 + 4 * HID * B;
    zero_ws<<<(nzero + TPB - 1) / TPB, TPB, 0, stream>>>(ws, nzero);
    rnn_fallback<<<NWG, TPB, 0, stream>>>(x, W1, bW1, U1, bU1,
                                          W2, bW2, U2, bU2, lw, lb, out, ws);
  }
}